// Round 1
// baseline (4341.437 us; speedup 1.0000x reference)
//
#include <hip/hip_runtime.h>
#include <hip/hip_bf16.h>
#include <math.h>

#define B_ 2
#define L_ 1024
#define DM 768
#define DI 1536
#define DS 16
#define DR 48
#define NL 4
#define VOC 32000
#define BL (B_*L_)
#define NCH 32
#define LCH (L_/NCH)
#define KSPLIT 4

__device__ __forceinline__ float sigmoidf_(float x){ return 1.f/(1.f+expf(-x)); }
__device__ __forceinline__ float siluf_(float x){ return x*sigmoidf_(x); }
__device__ __forceinline__ float softplusf_(float x){ return fmaxf(x,0.f) + log1pf(expf(-fabsf(x))); }

// ---------------- embedding gather ----------------
__global__ void embed_kernel(const int* __restrict__ idx, const float* __restrict__ emb,
                             float* __restrict__ x)
{
    int i = blockIdx.x*256 + threadIdx.x;        // over BL*DM
    if (i >= BL*DM) return;
    int c = i % DM; int bl = i / DM;
    x[i] = emb[(size_t)idx[bl]*DM + c];
}

// ---------------- rmsnorm (row per block) ----------------
__global__ void rmsnorm_kernel(const float* __restrict__ in, const float* __restrict__ w,
                               float* __restrict__ out)
{
    int row = blockIdx.x;                        // BL rows
    const float* xr = in + (size_t)row*DM;
    float ss = 0.f;
    for (int c = threadIdx.x; c < DM; c += 256) { float v = xr[c]; ss += v*v; }
    #pragma unroll
    for (int o = 32; o > 0; o >>= 1) ss += __shfl_down(ss, o, 64);
    __shared__ float red[4];
    if ((threadIdx.x & 63) == 0) red[threadIdx.x >> 6] = ss;
    __syncthreads();
    float tot = red[0] + red[1] + red[2] + red[3];
    float scale = rsqrtf(tot * (1.f/DM) + 1e-5f);
    float* o_ = out + (size_t)row*DM;
    for (int c = threadIdx.x; c < DM; c += 256) o_[c] = xr[c]*scale*w[c];
}

// ---------------- tile GEMM: C[m][n] = sum_k A[m][k]*W[n][k] (+epilogue) ----------------
// EPI: 0 = none, 1 = += extra[m][n] (residual), 2 = softplus(val + extra[n]) (bias)
// Requires M%128==0, N%128==0, K%8==0, lda/ldb multiples of 4.
template<int EPI>
__global__ __launch_bounds__(256) void gemm_tile(
    const float* __restrict__ A, int lda,
    const float* __restrict__ W, int ldb,
    float* __restrict__ C, int ldc,
    const float* __restrict__ extra,
    int K)
{
    __shared__ float As[8][128];
    __shared__ float Bs[8][128];
    const int bm = blockIdx.y * 128;
    const int bn = blockIdx.x * 128;
    const int tid = threadIdx.x;
    const int lr = tid >> 1;          // load row 0..127
    const int lh = (tid & 1) * 4;     // 0 or 4
    const int tr = tid >> 4;          // 0..15
    const int tc = tid & 15;          // 0..15

    float acc[8][8];
    #pragma unroll
    for (int i = 0; i < 8; i++)
        #pragma unroll
        for (int j = 0; j < 8; j++) acc[i][j] = 0.f;

    const float* Arow = A + (size_t)(bm + lr)*lda + lh;
    const float* Wrow = W + (size_t)(bn + lr)*ldb + lh;

    for (int k0 = 0; k0 < K; k0 += 8) {
        float4 av = *(const float4*)(Arow + k0);
        float4 wv = *(const float4*)(Wrow + k0);
        __syncthreads();
        As[lh+0][lr] = av.x; As[lh+1][lr] = av.y; As[lh+2][lr] = av.z; As[lh+3][lr] = av.w;
        Bs[lh+0][lr] = wv.x; Bs[lh+1][lr] = wv.y; Bs[lh+2][lr] = wv.z; Bs[lh+3][lr] = wv.w;
        __syncthreads();
        #pragma unroll
        for (int k = 0; k < 8; k++) {
            float a[8], b[8];
            *(float4*)(a)   = *(const float4*)&As[k][tr*8];
            *(float4*)(a+4) = *(const float4*)&As[k][tr*8+4];
            *(float4*)(b)   = *(const float4*)&Bs[k][tc*8];
            *(float4*)(b+4) = *(const float4*)&Bs[k][tc*8+4];
            #pragma unroll
            for (int i = 0; i < 8; i++)
                #pragma unroll
                for (int j = 0; j < 8; j++)
                    acc[i][j] = fmaf(a[i], b[j], acc[i][j]);
        }
    }

    #pragma unroll
    for (int i = 0; i < 8; i++) {
        int row = bm + tr*8 + i;
        float* crow = C + (size_t)row*ldc + bn + tc*8;
        float v[8];
        if (EPI == 0) {
            #pragma unroll
            for (int j = 0; j < 8; j++) v[j] = acc[i][j];
        } else if (EPI == 1) {
            const float* erow = extra + (size_t)row*ldc + bn + tc*8;
            #pragma unroll
            for (int j = 0; j < 8; j++) v[j] = acc[i][j] + erow[j];
        } else {
            const float* bia = extra + bn + tc*8;
            #pragma unroll
            for (int j = 0; j < 8; j++) v[j] = softplusf_(acc[i][j] + bia[j]);
        }
        *(float4*)(crow)   = make_float4(v[0],v[1],v[2],v[3]);
        *(float4*)(crow+4) = make_float4(v[4],v[5],v[6],v[7]);
    }
}

// ---------------- skinny split-K GEMM (N<=64, partial[z][m][n]) ----------------
// grid: x = N/16, y = M/64, z = KSPLIT. Requires K%(KSPLIT*32)==0.
__global__ __launch_bounds__(256) void gemm_skinny(
    const float* __restrict__ A, int lda,
    const float* __restrict__ W, int ldb,
    float* __restrict__ partial,
    int M, int N, int K)
{
    int klen = K / gridDim.z;
    int kbeg = blockIdx.z * klen;
    __shared__ float As[64][33];
    __shared__ float Ws[16][33];
    int tid = threadIdx.x;
    int bm = blockIdx.y*64, bn = blockIdx.x*16;
    int ar = tid >> 2, ak = (tid & 3)*8;   // A: 64 rows x 32k, 8 floats/thread
    int wr = tid >> 4, wk = (tid & 15)*2;  // W: 16 rows x 32k, 2 floats/thread
    int tr = tid >> 4, tc = tid & 15;      // out: rows tr*4+i, col tc

    float acc[4] = {0.f,0.f,0.f,0.f};
    for (int k0 = kbeg; k0 < kbeg + klen; k0 += 32) {
        float4 a0 = *(const float4*)(A + (size_t)(bm+ar)*lda + k0 + ak);
        float4 a1 = *(const float4*)(A + (size_t)(bm+ar)*lda + k0 + ak + 4);
        float2 wv = *(const float2*)(W + (size_t)(bn+wr)*ldb + k0 + wk);
        __syncthreads();
        As[ar][ak+0]=a0.x; As[ar][ak+1]=a0.y; As[ar][ak+2]=a0.z; As[ar][ak+3]=a0.w;
        As[ar][ak+4]=a1.x; As[ar][ak+5]=a1.y; As[ar][ak+6]=a1.z; As[ar][ak+7]=a1.w;
        Ws[wr][wk] = wv.x; Ws[wr][wk+1] = wv.y;
        __syncthreads();
        #pragma unroll 8
        for (int k = 0; k < 32; k++) {
            float b = Ws[tc][k];
            #pragma unroll
            for (int i = 0; i < 4; i++) acc[i] = fmaf(As[tr*4+i][k], b, acc[i]);
        }
    }
    #pragma unroll
    for (int i = 0; i < 4; i++)
        partial[((size_t)blockIdx.z*M + bm + tr*4 + i)*N + bn + tc] = acc[i];
}

__global__ void reduce_splitk(const float* __restrict__ partial, float* __restrict__ out, int MN)
{
    int i = blockIdx.x*256 + threadIdx.x;
    if (i >= MN) return;
    float s = 0.f;
    #pragma unroll
    for (int z = 0; z < KSPLIT; z++) s += partial[(size_t)z*MN + i];
    out[i] = s;
}

// ---------------- depthwise causal conv (k=4) + bias + silu ----------------
__global__ void conv_silu_kernel(const float* __restrict__ xr, const float* __restrict__ cw,
                                 const float* __restrict__ cb, float* __restrict__ t)
{
    int i = blockIdx.x*256 + threadIdx.x;     // over BL*DI
    if (i >= BL*DI) return;
    int d = i % DI; int bl = i / DI; int l = bl % L_; int b = bl / L_;
    const float* base = xr + (size_t)b*L_*(2*DI);
    float acc = cb[d];
    #pragma unroll
    for (int q = 0; q < 4; q++) {
        int ll = l - 3 + q;
        if (ll >= 0) acc = fmaf(base[(size_t)ll*(2*DI) + d], cw[d*4+q], acc);
    }
    t[i] = siluf_(acc);
}

// ---------------- chunked selective scan ----------------
// pass1: per (b,chunk,d): chunk summary P = prod a, S = local scan from 0
__global__ void scan_p1(const float* __restrict__ delta, const float* __restrict__ t,
                        const float* __restrict__ xdbl, const float* __restrict__ A_log,
                        float* __restrict__ Aprod, float* __restrict__ Bacc)
{
    int idx = blockIdx.x*256 + threadIdx.x;   // (b*NCH + c)*DI + d
    if (idx >= B_*NCH*DI) return;
    int d = idx % DI; int c = (idx/DI) % NCH; int b = idx/(DI*NCH);
    float Ad[16];
    #pragma unroll
    for (int n = 0; n < 16; n++) Ad[n] = -expf(A_log[d*16+n]);
    float P[16], S[16];
    #pragma unroll
    for (int n = 0; n < 16; n++) { P[n] = 1.f; S[n] = 0.f; }
    for (int s = 0; s < LCH; s++) {
        int bl = b*L_ + c*LCH + s;
        float dt = delta[(size_t)bl*DI + d];
        float u  = t[(size_t)bl*DI + d];
        const float* Bp = xdbl + (size_t)bl*64 + 48;
        #pragma unroll
        for (int n = 0; n < 16; n++) {
            float a  = expf(dt*Ad[n]);
            float bu = dt*Bp[n]*u;
            P[n] *= a;
            S[n] = fmaf(a, S[n], bu);
        }
    }
    size_t o = (size_t)idx*16;
    #pragma unroll
    for (int n = 0; n < 16; n++) { Aprod[o+n] = P[n]; Bacc[o+n] = S[n]; }
}

// pass2: per (b,d): scan over chunks, emit initial state per chunk
__global__ void scan_p2(const float* __restrict__ Aprod, const float* __restrict__ Bacc,
                        float* __restrict__ Hinit)
{
    int idx = blockIdx.x*256 + threadIdx.x;   // b*DI + d
    if (idx >= B_*DI) return;
    int d = idx % DI, b = idx / DI;
    float h[16];
    #pragma unroll
    for (int n = 0; n < 16; n++) h[n] = 0.f;
    for (int c = 0; c < NCH; c++) {
        size_t o = (((size_t)b*NCH + c)*DI + d)*16;
        #pragma unroll
        for (int n = 0; n < 16; n++) Hinit[o+n] = h[n];
        #pragma unroll
        for (int n = 0; n < 16; n++) h[n] = fmaf(Aprod[o+n], h[n], Bacc[o+n]);
    }
}

// pass3: replay chunk with correct initial state; fuse y = scan + u*D, z = y*silu(res)
__global__ void scan_p3(const float* __restrict__ delta, const float* __restrict__ t,
                        const float* __restrict__ xdbl, const float* __restrict__ Cb,
                        const float* __restrict__ A_log, const float* __restrict__ Dp,
                        const float* __restrict__ Hinit, const float* __restrict__ xr,
                        float* __restrict__ z)
{
    int idx = blockIdx.x*256 + threadIdx.x;
    if (idx >= B_*NCH*DI) return;
    int d = idx % DI; int c = (idx/DI) % NCH; int b = idx/(DI*NCH);
    float Ad[16];
    #pragma unroll
    for (int n = 0; n < 16; n++) Ad[n] = -expf(A_log[d*16+n]);
    float h[16];
    size_t ho = (size_t)idx*16;
    #pragma unroll
    for (int n = 0; n < 16; n++) h[n] = Hinit[ho+n];
    float Dd = Dp[d];
    for (int s = 0; s < LCH; s++) {
        int bl = b*L_ + c*LCH + s;
        float dt = delta[(size_t)bl*DI + d];
        float u  = t[(size_t)bl*DI + d];
        const float* Bp = xdbl + (size_t)bl*64 + 48;
        const float* Cp = Cb + (size_t)bl*16;
        float y = 0.f;
        #pragma unroll
        for (int n = 0; n < 16; n++) {
            float a = expf(dt*Ad[n]);
            h[n] = fmaf(a, h[n], dt*Bp[n]*u);
            y = fmaf(h[n], Cp[n], y);
        }
        y = fmaf(u, Dd, y);
        float r = xr[(size_t)bl*(2*DI) + DI + d];
        z[(size_t)bl*DI + d] = y * siluf_(r);
    }
}

// ---------------- host ----------------
extern "C" void kernel_launch(void* const* d_in, const int* in_sizes, int n_in,
                              void* d_out, int out_size, void* d_ws, size_t ws_size,
                              hipStream_t stream)
{
    const int*   text     = (const int*)  d_in[0];
    const float* visual   = (const float*)d_in[1];
    const float* emb      = (const float*)d_in[2];
    const float* norm_w   = (const float*)d_in[3];
    const float* norm_f_w = (const float*)d_in[4];
    const float* in_proj  = (const float*)d_in[5];
    const float* in_proj2 = (const float*)d_in[6];
    const float* conv_w   = (const float*)d_in[7];
    const float* conv_b   = (const float*)d_in[8];
    const float* x_proj   = (const float*)d_in[9];
    const float* c_proj   = (const float*)d_in[10];
    const float* dt_w     = (const float*)d_in[11];
    const float* dt_b     = (const float*)d_in[12];
    const float* A_log    = (const float*)d_in[13];
    const float* Dp       = (const float*)d_in[14];
    const float* out_proj = (const float*)d_in[15];
    float* out = (float*)d_out;

    // workspace layout (floats)
    float* ws = (float*)d_ws;
    size_t off = 0;
    float* x     = ws + off; off += (size_t)BL*DM;
    float* q     = ws + off; off += (size_t)BL*DM;
    float* v     = ws + off; off += (size_t)BL*DM;
    float* xn    = ws + off; off += (size_t)BL*DM;
    float* xr    = ws + off; off += (size_t)BL*2*DI;
    float* vin   = ws + off; off += (size_t)BL*DI;
    float* tb    = ws + off; off += (size_t)BL*DI;
    float* dl    = ws + off; off += (size_t)BL*DI;
    float* zb    = ws + off; off += (size_t)BL*DI;
    float* xdbl  = ws + off; off += (size_t)BL*64;
    float* Cb    = ws + off; off += (size_t)BL*16;
    float* Aprod = ws + off; off += (size_t)B_*NCH*DI*DS;
    float* Bacc  = ws + off; off += (size_t)B_*NCH*DI*DS;
    float* Hinit = ws + off; off += (size_t)B_*NCH*DI*DS;
    float* part  = ws + off; off += (size_t)KSPLIT*BL*64;

    dim3 blk(256);

    embed_kernel<<<dim3((BL*DM)/256), blk, 0, stream>>>(text, emb, x);

    for (int i = 0; i < NL; i++) {
        const float* nw = norm_w + (size_t)i*DM;
        rmsnorm_kernel<<<dim3(BL), blk, 0, stream>>>(x, nw, q);
        rmsnorm_kernel<<<dim3(BL), blk, 0, stream>>>(visual, nw, v);

        // xr = q @ in_proj^T  (2048 x 3072, K=768)
        gemm_tile<0><<<dim3(2*DI/128, BL/128), blk, 0, stream>>>(
            q, DM, in_proj + (size_t)i*2*DI*DM, DM, xr, 2*DI, nullptr, DM);
        // vin = v @ in_proj2^T (2048 x 1536, K=768)
        gemm_tile<0><<<dim3(DI/128, BL/128), blk, 0, stream>>>(
            v, DM, in_proj2 + (size_t)i*DI*DM, DM, vin, DI, nullptr, DM);

        conv_silu_kernel<<<dim3((BL*DI)/256), blk, 0, stream>>>(
            xr, conv_w + (size_t)i*DI*4, conv_b + (size_t)i*DI, tb);

        // x_dbl = t @ x_proj^T (2048 x 64, K=1536)
        gemm_skinny<<<dim3(64/16, BL/64, KSPLIT), blk, 0, stream>>>(
            tb, DI, x_proj + (size_t)i*(DR+DS)*DI, DI, part, BL, 64, DI);
        reduce_splitk<<<dim3((BL*64)/256), blk, 0, stream>>>(part, xdbl, BL*64);

        // C = vin @ c_proj^T (2048 x 16, K=1536)
        gemm_skinny<<<dim3(1, BL/64, KSPLIT), blk, 0, stream>>>(
            vin, DI, c_proj + (size_t)i*DS*DI, DI, part, BL, 16, DI);
        reduce_splitk<<<dim3((BL*16)/256), blk, 0, stream>>>(part, Cb, BL*16);

        // delta = softplus(x_dbl[:, :48] @ dt_w^T + dt_b) (2048 x 1536, K=48)
        gemm_tile<2><<<dim3(DI/128, BL/128), blk, 0, stream>>>(
            xdbl, 64, dt_w + (size_t)i*DI*DR, DR, dl, DI, dt_b + (size_t)i*DI, DR);

        // selective scan (chunked, 3 passes) -> z = (scan + u*D) * silu(res)
        const float* Al = A_log + (size_t)i*DI*DS;
        scan_p1<<<dim3((B_*NCH*DI)/256), blk, 0, stream>>>(dl, tb, xdbl, Al, Aprod, Bacc);
        scan_p2<<<dim3((B_*DI+255)/256), blk, 0, stream>>>(Aprod, Bacc, Hinit);
        scan_p3<<<dim3((B_*NCH*DI)/256), blk, 0, stream>>>(dl, tb, xdbl, Cb, Al,
            Dp + (size_t)i*DI, Hinit, xr, zb);

        // x = z @ out_proj^T + x (2048 x 768, K=1536)
        gemm_tile<1><<<dim3(DM/128, BL/128), blk, 0, stream>>>(
            zb, DI, out_proj + (size_t)i*DM*DI, DI, x, DM, x, DI);
    }

    rmsnorm_kernel<<<dim3(BL), blk, 0, stream>>>(x, norm_f_w, xn);
    // logits = xn @ emb^T (2048 x 32000, K=768)
    gemm_tile<0><<<dim3(VOC/128, BL/128), blk, 0, stream>>>(
        xn, DM, emb, DM, out, VOC, nullptr, DM);
}

// Round 3
// 1952.247 us; speedup vs baseline: 2.2238x; 2.2238x over previous
//
#include <hip/hip_runtime.h>
#include <hip/hip_bf16.h>
#include <math.h>

#define B_ 2
#define L_ 1024
#define DM 768
#define DI 1536
#define DS 16
#define DR 48
#define NL 4
#define VOC 32000
#define BL (B_*L_)
#define NCH 32
#define LCH (L_/NCH)
#define KSPLIT 4

typedef __attribute__((ext_vector_type(8))) short short8;
typedef __attribute__((ext_vector_type(4))) float f32x4;

__device__ __forceinline__ float sigmoidf_(float x){ return 1.f/(1.f+expf(-x)); }
__device__ __forceinline__ float siluf_(float x){ return x*sigmoidf_(x); }
__device__ __forceinline__ float softplusf_(float x){ return fmaxf(x,0.f) + log1pf(expf(-fabsf(x))); }
__device__ __forceinline__ unsigned short f2bf(float f){
    unsigned u = __float_as_uint(f);
    u += 0x7FFFu + ((u >> 16) & 1u);
    return (unsigned short)(u >> 16);
}
__device__ __forceinline__ float bf2f(unsigned short h){
    return __uint_as_float((unsigned)h << 16);
}
__device__ __forceinline__ void gload_lds16(const unsigned short* g, unsigned short* l){
    __builtin_amdgcn_global_load_lds(
        (const __attribute__((address_space(1))) void*)g,
        (__attribute__((address_space(3))) void*)l, 16, 0, 0);
}

// ---------------- fp32 -> bf16 cast (single) ----------------
__global__ void cast_bf16_kernel(const float* __restrict__ in, unsigned short* __restrict__ out, int n4)
{
    for (int i = blockIdx.x*256 + threadIdx.x; i < n4; i += gridDim.x*256) {
        float4 v = ((const float4*)in)[i];
        ushort4 o;
        o.x = f2bf(v.x); o.y = f2bf(v.y); o.z = f2bf(v.z); o.w = f2bf(v.w);
        ((ushort4*)out)[i] = o;
    }
}

// ---------------- fp32 -> bf16 hi/lo pair ----------------
__global__ void cast_pair_kernel(const float* __restrict__ in,
                                 unsigned short* __restrict__ hi,
                                 unsigned short* __restrict__ lo, int n4)
{
    for (int i = blockIdx.x*256 + threadIdx.x; i < n4; i += gridDim.x*256) {
        float4 v = ((const float4*)in)[i];
        ushort4 h, l;
        h.x = f2bf(v.x); l.x = f2bf(v.x - bf2f(h.x));
        h.y = f2bf(v.y); l.y = f2bf(v.y - bf2f(h.y));
        h.z = f2bf(v.z); l.z = f2bf(v.z - bf2f(h.z));
        h.w = f2bf(v.w); l.w = f2bf(v.w - bf2f(h.w));
        ((ushort4*)hi)[i] = h;
        ((ushort4*)lo)[i] = l;
    }
}

// ---------------- embedding gather ----------------
__global__ void embed_kernel(const int* __restrict__ idx, const float* __restrict__ emb,
                             float* __restrict__ x)
{
    int i = blockIdx.x*256 + threadIdx.x;        // over BL*DM
    if (i >= BL*DM) return;
    int c = i % DM; int bl = i / DM;
    x[i] = emb[(size_t)idx[bl]*DM + c];
}

// ---------------- rmsnorm; MODE: 0=f32 out, 1=bf16 out, 2=bf16 hi/lo out ------
template<int MODE>
__global__ void rmsnorm_kernel(const float* __restrict__ in, const float* __restrict__ w,
                               void* __restrict__ outv, void* __restrict__ outv2)
{
    int row = blockIdx.x;                        // BL rows
    const float* xr = in + (size_t)row*DM;
    float ss = 0.f;
    for (int c = threadIdx.x; c < DM; c += 256) { float v = xr[c]; ss += v*v; }
    #pragma unroll
    for (int o = 32; o > 0; o >>= 1) ss += __shfl_down(ss, o, 64);
    __shared__ float red[4];
    if ((threadIdx.x & 63) == 0) red[threadIdx.x >> 6] = ss;
    __syncthreads();
    float tot = red[0] + red[1] + red[2] + red[3];
    float scale = rsqrtf(tot * (1.f/DM) + 1e-5f);
    for (int c = threadIdx.x; c < DM; c += 256) {
        float v = xr[c]*scale*w[c];
        if (MODE == 0) ((float*)outv)[(size_t)row*DM + c] = v;
        else if (MODE == 1) ((unsigned short*)outv)[(size_t)row*DM + c] = f2bf(v);
        else {
            unsigned short h = f2bf(v);
            ((unsigned short*)outv)[(size_t)row*DM + c]  = h;
            ((unsigned short*)outv2)[(size_t)row*DM + c] = f2bf(v - bf2f(h));
        }
    }
}

// ---------------- bf16 MFMA GEMM (plain): C = A @ W^T ----------------
// 128x128 tile, BK=64, 4 waves (2x2, each 64x64 = 4x4 frags of 16x16x32).
// Linear LDS dest for global_load_lds; XOR swizzle via pre-swizzled GLOBAL
// source + swizzled ds_read (rule #21).
template<int EPI>
__global__ __launch_bounds__(256) void gemm_mfma(
    const unsigned short* __restrict__ A, int lda,
    const unsigned short* __restrict__ W, int ldb,
    float* __restrict__ C, int ldc,
    const float* __restrict__ extra,
    int K)
{
    __shared__ unsigned short As[128*64];
    __shared__ unsigned short Bs[128*64];
    const int tid = threadIdx.x;
    const int bm = blockIdx.y*128, bn = blockIdx.x*128;
    const int l  = tid & 63;
    const int w  = tid >> 6;
    const int wr = (w >> 1)*64, wc = (w & 1)*64;
    const int lr = l & 15, lg = l >> 4;

    f32x4 zero4 = {0.f, 0.f, 0.f, 0.f};
    f32x4 acc[4][4];
    #pragma unroll
    for (int m = 0; m < 4; m++)
        #pragma unroll
        for (int n = 0; n < 4; n++) acc[m][n] = zero4;

    for (int k0 = 0; k0 < K; k0 += 64) {
        __syncthreads();
        #pragma unroll
        for (int i = 0; i < 4; i++) {
            int c   = i*256 + tid;
            int row = c >> 3;
            int kb  = c & 7;
            int kbs = (kb ^ (row & 7)) << 3;
            gload_lds16(A + (size_t)(bm+row)*lda + k0 + kbs, &As[c*8]);
            gload_lds16(W + (size_t)(bn+row)*ldb + k0 + kbs, &Bs[c*8]);
        }
        __syncthreads();
        #pragma unroll
        for (int kk = 0; kk < 2; kk++) {
            short8 af[4], bfr[4];
            #pragma unroll
            for (int m = 0; m < 4; m++) {
                int row = wr + m*16 + lr;
                int kb  = kk*4 + lg;
                af[m] = *(const short8*)&As[row*64 + ((kb ^ (row & 7)) << 3)];
            }
            #pragma unroll
            for (int n = 0; n < 4; n++) {
                int row = wc + n*16 + lr;
                int kb  = kk*4 + lg;
                bfr[n] = *(const short8*)&Bs[row*64 + ((kb ^ (row & 7)) << 3)];
            }
            #pragma unroll
            for (int m = 0; m < 4; m++)
                #pragma unroll
                for (int n = 0; n < 4; n++)
                    acc[m][n] = __builtin_amdgcn_mfma_f32_16x16x32_bf16(af[m], bfr[n], acc[m][n], 0, 0, 0);
        }
    }

    // D layout: col = lane&15, row = (lane>>4)*4 + reg  [m89]
    #pragma unroll
    for (int m = 0; m < 4; m++) {
        #pragma unroll
        for (int n = 0; n < 4; n++) {
            int col = bn + wc + n*16 + lr;
            #pragma unroll
            for (int r = 0; r < 4; r++) {
                int rowi = bm + wr + m*16 + lg*4 + r;
                float v = acc[m][n][r];
                if (EPI == 1) v += extra[(size_t)rowi*ldc + col];
                C[(size_t)rowi*ldc + col] = v;
            }
        }
    }
}

// ---------------- split-bf16 (hi/lo) MFMA GEMM: fp32-quality ----------------
// C = (Ah+Al) @ (Wh+Wl)^T  ~= Ah@Wh + Ah@Wl + Al@Wh   (3 MFMA passes)
template<int EPI>
__global__ __launch_bounds__(256) void gemm_mfma2(
    const unsigned short* __restrict__ Ah, const unsigned short* __restrict__ Alo, int lda,
    const unsigned short* __restrict__ Wh, const unsigned short* __restrict__ Wlo, int ldb,
    float* __restrict__ C, int ldc,
    const float* __restrict__ extra,
    int K)
{
    __shared__ unsigned short Ash[128*64];
    __shared__ unsigned short Asl[128*64];
    __shared__ unsigned short Bsh[128*64];
    __shared__ unsigned short Bsl[128*64];
    const int tid = threadIdx.x;
    const int bm = blockIdx.y*128, bn = blockIdx.x*128;
    const int l  = tid & 63;
    const int w  = tid >> 6;
    const int wr = (w >> 1)*64, wc = (w & 1)*64;
    const int lr = l & 15, lg = l >> 4;

    f32x4 zero4 = {0.f, 0.f, 0.f, 0.f};
    f32x4 acc[4][4];
    #pragma unroll
    for (int m = 0; m < 4; m++)
        #pragma unroll
        for (int n = 0; n < 4; n++) acc[m][n] = zero4;

    for (int k0 = 0; k0 < K; k0 += 64) {
        __syncthreads();
        #pragma unroll
        for (int i = 0; i < 4; i++) {
            int c   = i*256 + tid;
            int row = c >> 3;
            int kb  = c & 7;
            int kbs = (kb ^ (row & 7)) << 3;
            const size_t ao = (size_t)(bm+row)*lda + k0 + kbs;
            const size_t bo = (size_t)(bn+row)*ldb + k0 + kbs;
            gload_lds16(Ah  + ao, &Ash[c*8]);
            gload_lds16(Alo + ao, &Asl[c*8]);
            gload_lds16(Wh  + bo, &Bsh[c*8]);
            gload_lds16(Wlo + bo, &Bsl[c*8]);
        }
        __syncthreads();
        #pragma unroll
        for (int kk = 0; kk < 2; kk++) {
            short8 ah[4], al[4], bh[4], bl[4];
            #pragma unroll
            for (int m = 0; m < 4; m++) {
                int row = wr + m*16 + lr;
                int so  = row*64 + (((kk*4 + lg) ^ (row & 7)) << 3);
                ah[m] = *(const short8*)&Ash[so];
                al[m] = *(const short8*)&Asl[so];
            }
            #pragma unroll
            for (int n = 0; n < 4; n++) {
                int row = wc + n*16 + lr;
                int so  = row*64 + (((kk*4 + lg) ^ (row & 7)) << 3);
                bh[n] = *(const short8*)&Bsh[so];
                bl[n] = *(const short8*)&Bsl[so];
            }
            #pragma unroll
            for (int m = 0; m < 4; m++)
                #pragma unroll
                for (int n = 0; n < 4; n++) {
                    acc[m][n] = __builtin_amdgcn_mfma_f32_16x16x32_bf16(al[m], bh[n], acc[m][n], 0, 0, 0);
                    acc[m][n] = __builtin_amdgcn_mfma_f32_16x16x32_bf16(ah[m], bl[n], acc[m][n], 0, 0, 0);
                    acc[m][n] = __builtin_amdgcn_mfma_f32_16x16x32_bf16(ah[m], bh[n], acc[m][n], 0, 0, 0);
                }
        }
    }

    #pragma unroll
    for (int m = 0; m < 4; m++) {
        #pragma unroll
        for (int n = 0; n < 4; n++) {
            int col = bn + wc + n*16 + lr;
            #pragma unroll
            for (int r = 0; r < 4; r++) {
                int rowi = bm + wr + m*16 + lg*4 + r;
                float v = acc[m][n][r];
                if (EPI == 1) v += extra[(size_t)rowi*ldc + col];
                C[(size_t)rowi*ldc + col] = v;
            }
        }
    }
}

// ---------------- fp32 tile GEMM (dt_proj, K=48) ----------------
template<int EPI>
__global__ __launch_bounds__(256) void gemm_tile(
    const float* __restrict__ A, int lda,
    const float* __restrict__ W, int ldb,
    float* __restrict__ C, int ldc,
    const float* __restrict__ extra,
    int K)
{
    __shared__ float As[8][128];
    __shared__ float Bs[8][128];
    const int bm = blockIdx.y * 128;
    const int bn = blockIdx.x * 128;
    const int tid = threadIdx.x;
    const int lr = tid >> 1;
    const int lh = (tid & 1) * 4;
    const int tr = tid >> 4;
    const int tc = tid & 15;

    float acc[8][8];
    #pragma unroll
    for (int i = 0; i < 8; i++)
        #pragma unroll
        for (int j = 0; j < 8; j++) acc[i][j] = 0.f;

    const float* Arow = A + (size_t)(bm + lr)*lda + lh;
    const float* Wrow = W + (size_t)(bn + lr)*ldb + lh;

    for (int k0 = 0; k0 < K; k0 += 8) {
        float4 av = *(const float4*)(Arow + k0);
        float4 wv = *(const float4*)(Wrow + k0);
        __syncthreads();
        As[lh+0][lr] = av.x; As[lh+1][lr] = av.y; As[lh+2][lr] = av.z; As[lh+3][lr] = av.w;
        Bs[lh+0][lr] = wv.x; Bs[lh+1][lr] = wv.y; Bs[lh+2][lr] = wv.z; Bs[lh+3][lr] = wv.w;
        __syncthreads();
        #pragma unroll
        for (int k = 0; k < 8; k++) {
            float a[8], b[8];
            *(float4*)(a)   = *(const float4*)&As[k][tr*8];
            *(float4*)(a+4) = *(const float4*)&As[k][tr*8+4];
            *(float4*)(b)   = *(const float4*)&Bs[k][tc*8];
            *(float4*)(b+4) = *(const float4*)&Bs[k][tc*8+4];
            #pragma unroll
            for (int i = 0; i < 8; i++)
                #pragma unroll
                for (int j = 0; j < 8; j++)
                    acc[i][j] = fmaf(a[i], b[j], acc[i][j]);
        }
    }

    #pragma unroll
    for (int i = 0; i < 8; i++) {
        int row = bm + tr*8 + i;
        float* crow = C + (size_t)row*ldc + bn + tc*8;
        float v[8];
        if (EPI == 2) {
            const float* bia = extra + bn + tc*8;
            #pragma unroll
            for (int j = 0; j < 8; j++) v[j] = softplusf_(acc[i][j] + bia[j]);
        } else {
            #pragma unroll
            for (int j = 0; j < 8; j++) v[j] = acc[i][j];
        }
        *(float4*)(crow)   = make_float4(v[0],v[1],v[2],v[3]);
        *(float4*)(crow+4) = make_float4(v[4],v[5],v[6],v[7]);
    }
}

// ---------------- skinny split-K GEMM (N<=64) ----------------
__global__ __launch_bounds__(256) void gemm_skinny(
    const float* __restrict__ A, int lda,
    const float* __restrict__ W, int ldb,
    float* __restrict__ partial,
    int M, int N, int K)
{
    int klen = K / gridDim.z;
    int kbeg = blockIdx.z * klen;
    __shared__ float As[64][33];
    __shared__ float Ws[16][33];
    int tid = threadIdx.x;
    int bm = blockIdx.y*64, bn = blockIdx.x*16;
    int ar = tid >> 2, ak = (tid & 3)*8;
    int wr = tid >> 4, wk = (tid & 15)*2;
    int tr = tid >> 4, tc = tid & 15;

    float acc[4] = {0.f,0.f,0.f,0.f};
    for (int k0 = kbeg; k0 < kbeg + klen; k0 += 32) {
        float4 a0 = *(const float4*)(A + (size_t)(bm+ar)*lda + k0 + ak);
        float4 a1 = *(const float4*)(A + (size_t)(bm+ar)*lda + k0 + ak + 4);
        float2 wv = *(const float2*)(W + (size_t)(bn+wr)*ldb + k0 + wk);
        __syncthreads();
        As[ar][ak+0]=a0.x; As[ar][ak+1]=a0.y; As[ar][ak+2]=a0.z; As[ar][ak+3]=a0.w;
        As[ar][ak+4]=a1.x; As[ar][ak+5]=a1.y; As[ar][ak+6]=a1.z; As[ar][ak+7]=a1.w;
        Ws[wr][wk] = wv.x; Ws[wr][wk+1] = wv.y;
        __syncthreads();
        #pragma unroll 8
        for (int k = 0; k < 32; k++) {
            float b = Ws[tc][k];
            #pragma unroll
            for (int i = 0; i < 4; i++) acc[i] = fmaf(As[tr*4+i][k], b, acc[i]);
        }
    }
    #pragma unroll
    for (int i = 0; i < 4; i++)
        partial[((size_t)blockIdx.z*M + bm + tr*4 + i)*N + bn + tc] = acc[i];
}

__global__ void reduce_splitk(const float* __restrict__ partial, float* __restrict__ out, int MN)
{
    int i = blockIdx.x*256 + threadIdx.x;
    if (i >= MN) return;
    float s = 0.f;
    #pragma unroll
    for (int z = 0; z < KSPLIT; z++) s += partial[(size_t)z*MN + i];
    out[i] = s;
}

// ---------------- depthwise causal conv (k=4) + bias + silu ----------------
__global__ void conv_silu_kernel(const float* __restrict__ xr, const float* __restrict__ cw,
                                 const float* __restrict__ cb, float* __restrict__ t)
{
    int i = blockIdx.x*256 + threadIdx.x;     // over BL*DI
    if (i >= BL*DI) return;
    int d = i % DI; int bl = i / DI; int l = bl % L_; int b = bl / L_;
    const float* base = xr + (size_t)b*L_*(2*DI);
    float acc = cb[d];
    #pragma unroll
    for (int q = 0; q < 4; q++) {
        int ll = l - 3 + q;
        if (ll >= 0) acc = fmaf(base[(size_t)ll*(2*DI) + d], cw[d*4+q], acc);
    }
    t[i] = siluf_(acc);
}

// ---------------- chunked selective scan ----------------
__global__ void scan_p1(const float* __restrict__ delta, const float* __restrict__ t,
                        const float* __restrict__ xdbl, const float* __restrict__ A_log,
                        float* __restrict__ Aprod, float* __restrict__ Bacc)
{
    int idx = blockIdx.x*256 + threadIdx.x;   // (b*NCH + c)*DI + d
    if (idx >= B_*NCH*DI) return;
    int d = idx % DI; int c = (idx/DI) % NCH; int b = idx/(DI*NCH);
    float Ad[16];
    #pragma unroll
    for (int n = 0; n < 16; n++) Ad[n] = -expf(A_log[d*16+n]);
    float P[16], S[16];
    #pragma unroll
    for (int n = 0; n < 16; n++) { P[n] = 1.f; S[n] = 0.f; }
    for (int s = 0; s < LCH; s++) {
        int bl = b*L_ + c*LCH + s;
        float dt = delta[(size_t)bl*DI + d];
        float u  = t[(size_t)bl*DI + d];
        const float* Bp = xdbl + (size_t)bl*64 + 48;
        #pragma unroll
        for (int n = 0; n < 16; n++) {
            float a  = expf(dt*Ad[n]);
            float bu = dt*Bp[n]*u;
            P[n] *= a;
            S[n] = fmaf(a, S[n], bu);
        }
    }
    size_t o = (size_t)idx*16;
    #pragma unroll
    for (int n = 0; n < 16; n++) { Aprod[o+n] = P[n]; Bacc[o+n] = S[n]; }
}

__global__ void scan_p2(const float* __restrict__ Aprod, const float* __restrict__ Bacc,
                        float* __restrict__ Hinit)
{
    int idx = blockIdx.x*256 + threadIdx.x;   // b*DI + d
    if (idx >= B_*DI) return;
    int d = idx % DI, b = idx / DI;
    float h[16];
    #pragma unroll
    for (int n = 0; n < 16; n++) h[n] = 0.f;
    for (int c = 0; c < NCH; c++) {
        size_t o = (((size_t)b*NCH + c)*DI + d)*16;
        #pragma unroll
        for (int n = 0; n < 16; n++) Hinit[o+n] = h[n];
        #pragma unroll
        for (int n = 0; n < 16; n++) h[n] = fmaf(Aprod[o+n], h[n], Bacc[o+n]);
    }
}

// pass3: replay + fuse y = scan + u*D, z = y*silu(res) -> bf16 hi/lo out
__global__ void scan_p3(const float* __restrict__ delta, const float* __restrict__ t,
                        const float* __restrict__ xdbl, const float* __restrict__ Cb,
                        const float* __restrict__ A_log, const float* __restrict__ Dp,
                        const float* __restrict__ Hinit, const float* __restrict__ xr,
                        unsigned short* __restrict__ zh, unsigned short* __restrict__ zl)
{
    int idx = blockIdx.x*256 + threadIdx.x;
    if (idx >= B_*NCH*DI) return;
    int d = idx % DI; int c = (idx/DI) % NCH; int b = idx/(DI*NCH);
    float Ad[16];
    #pragma unroll
    for (int n = 0; n < 16; n++) Ad[n] = -expf(A_log[d*16+n]);
    float h[16];
    size_t ho = (size_t)idx*16;
    #pragma unroll
    for (int n = 0; n < 16; n++) h[n] = Hinit[ho+n];
    float Dd = Dp[d];
    for (int s = 0; s < LCH; s++) {
        int bl = b*L_ + c*LCH + s;
        float dt = delta[(size_t)bl*DI + d];
        float u  = t[(size_t)bl*DI + d];
        const float* Bp = xdbl + (size_t)bl*64 + 48;
        const float* Cp = Cb + (size_t)bl*16;
        float y = 0.f;
        #pragma unroll
        for (int n = 0; n < 16; n++) {
            float a = expf(dt*Ad[n]);
            h[n] = fmaf(a, h[n], dt*Bp[n]*u);
            y = fmaf(h[n], Cp[n], y);
        }
        y = fmaf(u, Dd, y);
        float r = xr[(size_t)bl*(2*DI) + DI + d];
        float zv = y * siluf_(r);
        unsigned short hh = f2bf(zv);
        zh[(size_t)bl*DI + d] = hh;
        zl[(size_t)bl*DI + d] = f2bf(zv - bf2f(hh));
    }
}

// ---------------- host ----------------
extern "C" void kernel_launch(void* const* d_in, const int* in_sizes, int n_in,
                              void* d_out, int out_size, void* d_ws, size_t ws_size,
                              hipStream_t stream)
{
    const int*   text     = (const int*)  d_in[0];
    const float* visual   = (const float*)d_in[1];
    const float* emb      = (const float*)d_in[2];
    const float* norm_w   = (const float*)d_in[3];
    const float* norm_f_w = (const float*)d_in[4];
    const float* in_proj  = (const float*)d_in[5];
    const float* in_proj2 = (const float*)d_in[6];
    const float* conv_w   = (const float*)d_in[7];
    const float* conv_b   = (const float*)d_in[8];
    const float* x_proj   = (const float*)d_in[9];
    const float* c_proj   = (const float*)d_in[10];
    const float* dt_w     = (const float*)d_in[11];
    const float* dt_b     = (const float*)d_in[12];
    const float* A_log    = (const float*)d_in[13];
    const float* Dp       = (const float*)d_in[14];
    const float* out_proj = (const float*)d_in[15];
    float* out = (float*)d_out;

    // workspace layout (floats first)
    float* ws = (float*)d_ws;
    size_t off = 0;
    float* x     = ws + off; off += (size_t)BL*DM;
    float* xr    = ws + off; off += (size_t)BL*2*DI;
    float* vin   = ws + off; off += (size_t)BL*DI;
    float* tb    = ws + off; off += (size_t)BL*DI;
    float* dl    = ws + off; off += (size_t)BL*DI;
    float* xdbl  = ws + off; off += (size_t)BL*64;
    float* Cb    = ws + off; off += (size_t)BL*16;
    float* Aprod = ws + off; off += (size_t)B_*NCH*DI*DS;
    float* Bacc  = ws + off; off += (size_t)B_*NCH*DI*DS;
    float* Hinit = ws + off; off += (size_t)B_*NCH*DI*DS;
    float* part  = ws + off; off += (size_t)KSPLIT*BL*64;

    unsigned short* bfb = (unsigned short*)(ws + off);
    size_t bo = 0;
    unsigned short* emb_bf = bfb + bo; bo += (size_t)VOC*DM;
    unsigned short* wA_h   = bfb + bo; bo += (size_t)2*DI*DM;
    unsigned short* wA_l   = bfb + bo; bo += (size_t)2*DI*DM;
    unsigned short* wB_h   = bfb + bo; bo += (size_t)DI*DM;
    unsigned short* wB_l   = bfb + bo; bo += (size_t)DI*DM;
    unsigned short* wO_h   = bfb + bo; bo += (size_t)DM*DI;
    unsigned short* wO_l   = bfb + bo; bo += (size_t)DM*DI;
    unsigned short* q_h    = bfb + bo; bo += (size_t)BL*DM;
    unsigned short* q_l    = bfb + bo; bo += (size_t)BL*DM;
    unsigned short* v_h    = bfb + bo; bo += (size_t)BL*DM;
    unsigned short* v_l    = bfb + bo; bo += (size_t)BL*DM;
    unsigned short* z_h    = bfb + bo; bo += (size_t)BL*DI;
    unsigned short* z_l    = bfb + bo; bo += (size_t)BL*DI;
    unsigned short* xn_bf  = bfb + bo; bo += (size_t)BL*DM;

    dim3 blk(256);
    dim3 cgrid(2048);

    // embedding cast once (lm_head B operand)
    cast_bf16_kernel<<<cgrid, blk, 0, stream>>>(emb, emb_bf, VOC*DM/4);

    embed_kernel<<<dim3((BL*DM)/256), blk, 0, stream>>>(text, emb, x);

    for (int i = 0; i < NL; i++) {
        const float* nw = norm_w + (size_t)i*DM;
        rmsnorm_kernel<2><<<dim3(BL), blk, 0, stream>>>(x, nw, q_h, q_l);
        rmsnorm_kernel<2><<<dim3(BL), blk, 0, stream>>>(visual, nw, v_h, v_l);

        // per-layer weight hi/lo casts
        cast_pair_kernel<<<cgrid, blk, 0, stream>>>(in_proj  + (size_t)i*2*DI*DM, wA_h, wA_l, 2*DI*DM/4);
        cast_pair_kernel<<<cgrid, blk, 0, stream>>>(in_proj2 + (size_t)i*DI*DM,   wB_h, wB_l, DI*DM/4);
        cast_pair_kernel<<<cgrid, blk, 0, stream>>>(out_proj + (size_t)i*DM*DI,   wO_h, wO_l, DM*DI/4);

        // xr = q @ in_proj^T  (2048 x 3072, K=768) -- split precision
        gemm_mfma2<0><<<dim3(2*DI/128, BL/128), blk, 0, stream>>>(
            q_h, q_l, DM, wA_h, wA_l, DM, xr, 2*DI, nullptr, DM);
        // vin = v @ in_proj2^T (2048 x 1536, K=768) -- split precision
        gemm_mfma2<0><<<dim3(DI/128, BL/128), blk, 0, stream>>>(
            v_h, v_l, DM, wB_h, wB_l, DM, vin, DI, nullptr, DM);

        conv_silu_kernel<<<dim3((BL*DI)/256), blk, 0, stream>>>(
            xr, conv_w + (size_t)i*DI*4, conv_b + (size_t)i*DI, tb);

        // x_dbl = t @ x_proj^T (2048 x 64, K=1536) fp32
        gemm_skinny<<<dim3(64/16, BL/64, KSPLIT), blk, 0, stream>>>(
            tb, DI, x_proj + (size_t)i*(DR+DS)*DI, DI, part, BL, 64, DI);
        reduce_splitk<<<dim3((BL*64)/256), blk, 0, stream>>>(part, xdbl, BL*64);

        // C = vin @ c_proj^T (2048 x 16, K=1536) fp32
        gemm_skinny<<<dim3(1, BL/64, KSPLIT), blk, 0, stream>>>(
            vin, DI, c_proj + (size_t)i*DS*DI, DI, part, BL, 16, DI);
        reduce_splitk<<<dim3((BL*16)/256), blk, 0, stream>>>(part, Cb, BL*16);

        // delta = softplus(x_dbl[:, :48] @ dt_w^T + dt_b) fp32
        gemm_tile<2><<<dim3(DI/128, BL/128), blk, 0, stream>>>(
            xdbl, 64, dt_w + (size_t)i*DI*DR, DR, dl, DI, dt_b + (size_t)i*DI, DR);

        // selective scan (chunked, 3 passes) -> z hi/lo
        const float* Al = A_log + (size_t)i*DI*DS;
        scan_p1<<<dim3((B_*NCH*DI)/256), blk, 0, stream>>>(dl, tb, xdbl, Al, Aprod, Bacc);
        scan_p2<<<dim3((B_*DI+255)/256), blk, 0, stream>>>(Aprod, Bacc, Hinit);
        scan_p3<<<dim3((B_*NCH*DI)/256), blk, 0, stream>>>(dl, tb, xdbl, Cb, Al,
            Dp + (size_t)i*DI, Hinit, xr, z_h, z_l);

        // x = z @ out_proj^T + x (2048 x 768, K=1536) -- split precision
        gemm_mfma2<1><<<dim3(DM/128, BL/128), blk, 0, stream>>>(
            z_h, z_l, DI, wO_h, wO_l, DI, x, DM, x, DI);
    }

    rmsnorm_kernel<1><<<dim3(BL), blk, 0, stream>>>(x, norm_f_w, xn_bf, nullptr);
    // logits = xn @ emb^T (2048 x 32000, K=768) -- plain bf16 (output-only error)
    gemm_mfma<0><<<dim3(VOC/128, BL/128), blk, 0, stream>>>(
        xn_bf, DM, emb_bf, DM, out, VOC, nullptr, DM);
}

// Round 4
// 1721.326 us; speedup vs baseline: 2.5221x; 1.1342x over previous
//
#include <hip/hip_runtime.h>
#include <hip/hip_bf16.h>
#include <math.h>

#define B_ 2
#define L_ 1024
#define DM 768
#define DI 1536
#define DS 16
#define DR 48
#define NL 4
#define VOC 32000
#define BL (B_*L_)
#define NCH 32
#define LCH (L_/NCH)
#define KSPLIT 4
#define NXD 80   // fused x_dbl(64) + C(16) columns

typedef __attribute__((ext_vector_type(8))) short short8;
typedef __attribute__((ext_vector_type(4))) float f32x4;

__device__ __forceinline__ float sigmoidf_(float x){ return 1.f/(1.f+expf(-x)); }
__device__ __forceinline__ float siluf_(float x){ return x*sigmoidf_(x); }
__device__ __forceinline__ float softplusf_(float x){ return fmaxf(x,0.f) + log1pf(expf(-fabsf(x))); }
__device__ __forceinline__ unsigned short f2bf(float f){
    unsigned u = __float_as_uint(f);
    u += 0x7FFFu + ((u >> 16) & 1u);
    return (unsigned short)(u >> 16);
}
__device__ __forceinline__ float bf2f(unsigned short h){
    return __uint_as_float((unsigned)h << 16);
}
__device__ __forceinline__ void gload_lds16(const unsigned short* g, unsigned short* l){
    __builtin_amdgcn_global_load_lds(
        (const __attribute__((address_space(1))) void*)g,
        (__attribute__((address_space(3))) void*)l, 16, 0, 0);
}

// ---------------- fp32 -> bf16 cast (single) ----------------
__global__ void cast_bf16_kernel(const float* __restrict__ in, unsigned short* __restrict__ out, int n4)
{
    for (int i = blockIdx.x*256 + threadIdx.x; i < n4; i += gridDim.x*256) {
        float4 v = ((const float4*)in)[i];
        ushort4 o;
        o.x = f2bf(v.x); o.y = f2bf(v.y); o.z = f2bf(v.z); o.w = f2bf(v.w);
        ((ushort4*)out)[i] = o;
    }
}

// ---------------- fp32 -> bf16 hi/lo for 3 arrays in one dispatch ----------------
__global__ void cast_pair3_kernel(
    const float* __restrict__ s1, unsigned short* __restrict__ h1, unsigned short* __restrict__ l1, int n1,
    const float* __restrict__ s2, unsigned short* __restrict__ h2, unsigned short* __restrict__ l2, int n2,
    const float* __restrict__ s3, unsigned short* __restrict__ h3, unsigned short* __restrict__ l3, int n3)
{
    int total = n1 + n2 + n3;
    for (int i = blockIdx.x*256 + threadIdx.x; i < total; i += gridDim.x*256) {
        const float* s; unsigned short *h, *l; int j;
        if (i < n1)           { s = s1; h = h1; l = l1; j = i; }
        else if (i < n1 + n2) { s = s2; h = h2; l = l2; j = i - n1; }
        else                  { s = s3; h = h3; l = l3; j = i - n1 - n2; }
        float4 v = ((const float4*)s)[j];
        ushort4 hh, ll;
        hh.x = f2bf(v.x); ll.x = f2bf(v.x - bf2f(hh.x));
        hh.y = f2bf(v.y); ll.y = f2bf(v.y - bf2f(hh.y));
        hh.z = f2bf(v.z); ll.z = f2bf(v.z - bf2f(hh.z));
        hh.w = f2bf(v.w); ll.w = f2bf(v.w - bf2f(hh.w));
        ((ushort4*)h)[j] = hh;
        ((ushort4*)l)[j] = ll;
    }
}

// ---------------- embedding gather ----------------
__global__ void embed_kernel(const int* __restrict__ idx, const float* __restrict__ emb,
                             float* __restrict__ x)
{
    int i = blockIdx.x*256 + threadIdx.x;        // over BL*DM
    if (i >= BL*DM) return;
    int c = i % DM; int bl = i / DM;
    x[i] = emb[(size_t)idx[bl]*DM + c];
}

// ---------------- rmsnorm single (bf16 out) ----------------
__global__ void rmsnorm_bf_kernel(const float* __restrict__ in, const float* __restrict__ w,
                                  unsigned short* __restrict__ out)
{
    int row = blockIdx.x;
    const float* xr = in + (size_t)row*DM;
    float ss = 0.f;
    for (int c = threadIdx.x; c < DM; c += 256) { float v = xr[c]; ss += v*v; }
    #pragma unroll
    for (int o = 32; o > 0; o >>= 1) ss += __shfl_down(ss, o, 64);
    __shared__ float red[4];
    if ((threadIdx.x & 63) == 0) red[threadIdx.x >> 6] = ss;
    __syncthreads();
    float tot = red[0] + red[1] + red[2] + red[3];
    float scale = rsqrtf(tot * (1.f/DM) + 1e-5f);
    for (int c = threadIdx.x; c < DM; c += 256)
        out[(size_t)row*DM + c] = f2bf(xr[c]*scale*w[c]);
}

// ---------------- rmsnorm dual (q from x, v from visual), hi/lo bf16 out ------
__global__ void rmsnorm_dual_kernel(const float* __restrict__ x, const float* __restrict__ vis,
                                    const float* __restrict__ w,
                                    unsigned short* __restrict__ qh, unsigned short* __restrict__ ql,
                                    unsigned short* __restrict__ vh, unsigned short* __restrict__ vl)
{
    int row = blockIdx.x;                        // 0..2*BL-1
    bool first = row < BL;
    int r = first ? row : row - BL;
    const float* xr = (first ? x : vis) + (size_t)r*DM;
    unsigned short* oh = (first ? qh : vh) + (size_t)r*DM;
    unsigned short* ol = (first ? ql : vl) + (size_t)r*DM;
    float ss = 0.f;
    for (int c = threadIdx.x; c < DM; c += 256) { float v = xr[c]; ss += v*v; }
    #pragma unroll
    for (int o = 32; o > 0; o >>= 1) ss += __shfl_down(ss, o, 64);
    __shared__ float red[4];
    if ((threadIdx.x & 63) == 0) red[threadIdx.x >> 6] = ss;
    __syncthreads();
    float tot = red[0] + red[1] + red[2] + red[3];
    float scale = rsqrtf(tot * (1.f/DM) + 1e-5f);
    for (int c = threadIdx.x; c < DM; c += 256) {
        float v = xr[c]*scale*w[c];
        unsigned short h = f2bf(v);
        oh[c] = h;
        ol[c] = f2bf(v - bf2f(h));
    }
}

// ---------------- lm_head bf16 MFMA GEMM (grid x=M/128, y=N/128) ----------------
// XCD-chunked bijective swizzle (m204) + nontemporal C stores (write-stream
// does not pollute L2/L3, keeps B resident).
__global__ __launch_bounds__(256) void gemm_head(
    const unsigned short* __restrict__ A, int lda,
    const unsigned short* __restrict__ W, int ldb,
    float* __restrict__ C, int ldc, int K)
{
    __shared__ unsigned short As[128*64];
    __shared__ unsigned short Bs[128*64];
    const int tid = threadIdx.x;

    int nwg  = gridDim.x*gridDim.y;
    int flat = blockIdx.y*gridDim.x + blockIdx.x;
    if ((nwg & 7) == 0) {
        int q = nwg >> 3;
        flat = (flat & 7)*q + (flat >> 3);   // contiguous logical chunk per XCD
    }
    const int bm = (flat % gridDim.x)*128;
    const int bn = (flat / gridDim.x)*128;

    const int l  = tid & 63;
    const int w  = tid >> 6;
    const int wr = (w >> 1)*64, wc = (w & 1)*64;
    const int lr = l & 15, lg = l >> 4;

    f32x4 zero4 = {0.f, 0.f, 0.f, 0.f};
    f32x4 acc[4][4];
    #pragma unroll
    for (int m = 0; m < 4; m++)
        #pragma unroll
        for (int n = 0; n < 4; n++) acc[m][n] = zero4;

    for (int k0 = 0; k0 < K; k0 += 64) {
        __syncthreads();
        #pragma unroll
        for (int i = 0; i < 4; i++) {
            int c   = i*256 + tid;
            int row = c >> 3;
            int kb  = c & 7;
            int kbs = (kb ^ (row & 7)) << 3;
            gload_lds16(A + (size_t)(bm+row)*lda + k0 + kbs, &As[c*8]);
            gload_lds16(W + (size_t)(bn+row)*ldb + k0 + kbs, &Bs[c*8]);
        }
        __syncthreads();
        #pragma unroll
        for (int kk = 0; kk < 2; kk++) {
            short8 af[4], bfr[4];
            #pragma unroll
            for (int m = 0; m < 4; m++) {
                int row = wr + m*16 + lr;
                af[m] = *(const short8*)&As[row*64 + (((kk*4+lg) ^ (row & 7)) << 3)];
            }
            #pragma unroll
            for (int n = 0; n < 4; n++) {
                int row = wc + n*16 + lr;
                bfr[n] = *(const short8*)&Bs[row*64 + (((kk*4+lg) ^ (row & 7)) << 3)];
            }
            #pragma unroll
            for (int m = 0; m < 4; m++)
                #pragma unroll
                for (int n = 0; n < 4; n++)
                    acc[m][n] = __builtin_amdgcn_mfma_f32_16x16x32_bf16(af[m], bfr[n], acc[m][n], 0, 0, 0);
        }
    }

    #pragma unroll
    for (int m = 0; m < 4; m++)
        #pragma unroll
        for (int n = 0; n < 4; n++) {
            int col = bn + wc + n*16 + lr;
            #pragma unroll
            for (int r = 0; r < 4; r++) {
                int rowi = bm + wr + m*16 + lg*4 + r;
                __builtin_nontemporal_store(acc[m][n][r], &C[(size_t)rowi*ldc + col]);
            }
        }
}

// ---------------- split-bf16 (hi/lo) MFMA GEMM core ----------------
template<int EPI>
__device__ __forceinline__ void mfma2_body(
    const unsigned short* __restrict__ Ah, const unsigned short* __restrict__ Alo, int lda,
    const unsigned short* __restrict__ Wh, const unsigned short* __restrict__ Wlo, int ldb,
    float* __restrict__ C, int ldc, const float* __restrict__ extra,
    int K, int bm, int bn,
    unsigned short* Ash, unsigned short* Asl, unsigned short* Bsh, unsigned short* Bsl)
{
    const int tid = threadIdx.x;
    const int l  = tid & 63;
    const int w  = tid >> 6;
    const int wr = (w >> 1)*64, wc = (w & 1)*64;
    const int lr = l & 15, lg = l >> 4;

    f32x4 zero4 = {0.f, 0.f, 0.f, 0.f};
    f32x4 acc[4][4];
    #pragma unroll
    for (int m = 0; m < 4; m++)
        #pragma unroll
        for (int n = 0; n < 4; n++) acc[m][n] = zero4;

    for (int k0 = 0; k0 < K; k0 += 64) {
        __syncthreads();
        #pragma unroll
        for (int i = 0; i < 4; i++) {
            int c   = i*256 + tid;
            int row = c >> 3;
            int kb  = c & 7;
            int kbs = (kb ^ (row & 7)) << 3;
            const size_t ao = (size_t)(bm+row)*lda + k0 + kbs;
            const size_t bo = (size_t)(bn+row)*ldb + k0 + kbs;
            gload_lds16(Ah  + ao, &Ash[c*8]);
            gload_lds16(Alo + ao, &Asl[c*8]);
            gload_lds16(Wh  + bo, &Bsh[c*8]);
            gload_lds16(Wlo + bo, &Bsl[c*8]);
        }
        __syncthreads();
        #pragma unroll
        for (int kk = 0; kk < 2; kk++) {
            short8 ah[4], al[4], bh[4], bl[4];
            #pragma unroll
            for (int m = 0; m < 4; m++) {
                int row = wr + m*16 + lr;
                int so  = row*64 + (((kk*4 + lg) ^ (row & 7)) << 3);
                ah[m] = *(const short8*)&Ash[so];
                al[m] = *(const short8*)&Asl[so];
            }
            #pragma unroll
            for (int n = 0; n < 4; n++) {
                int row = wc + n*16 + lr;
                int so  = row*64 + (((kk*4 + lg) ^ (row & 7)) << 3);
                bh[n] = *(const short8*)&Bsh[so];
                bl[n] = *(const short8*)&Bsl[so];
            }
            #pragma unroll
            for (int m = 0; m < 4; m++)
                #pragma unroll
                for (int n = 0; n < 4; n++) {
                    acc[m][n] = __builtin_amdgcn_mfma_f32_16x16x32_bf16(al[m], bh[n], acc[m][n], 0, 0, 0);
                    acc[m][n] = __builtin_amdgcn_mfma_f32_16x16x32_bf16(ah[m], bl[n], acc[m][n], 0, 0, 0);
                    acc[m][n] = __builtin_amdgcn_mfma_f32_16x16x32_bf16(ah[m], bh[n], acc[m][n], 0, 0, 0);
                }
        }
    }

    #pragma unroll
    for (int m = 0; m < 4; m++)
        #pragma unroll
        for (int n = 0; n < 4; n++) {
            int col = bn + wc + n*16 + lr;
            #pragma unroll
            for (int r = 0; r < 4; r++) {
                int rowi = bm + wr + m*16 + lg*4 + r;
                float v = acc[m][n][r];
                if (EPI == 1) v += extra[(size_t)rowi*ldc + col];
                C[(size_t)rowi*ldc + col] = v;
            }
        }
}

// single split GEMM (out_proj, EPI=1 residual)
template<int EPI>
__global__ __launch_bounds__(256) void gemm_mfma2(
    const unsigned short* __restrict__ Ah, const unsigned short* __restrict__ Alo, int lda,
    const unsigned short* __restrict__ Wh, const unsigned short* __restrict__ Wlo, int ldb,
    float* __restrict__ C, int ldc, const float* __restrict__ extra, int K)
{
    __shared__ unsigned short Ash[128*64];
    __shared__ unsigned short Asl[128*64];
    __shared__ unsigned short Bsh[128*64];
    __shared__ unsigned short Bsl[128*64];
    mfma2_body<EPI>(Ah, Alo, lda, Wh, Wlo, ldb, C, ldc, extra, K,
                    blockIdx.y*128, blockIdx.x*128, Ash, Asl, Bsh, Bsl);
}

// dual split GEMM: blocks [0,nb1) -> GEMM1, [nb1,..) -> GEMM2 (shared lda/ldb/K)
__global__ __launch_bounds__(256) void gemm_mfma2_dual(
    const unsigned short* __restrict__ Ah1, const unsigned short* __restrict__ Al1,
    const unsigned short* __restrict__ Wh1, const unsigned short* __restrict__ Wl1,
    float* __restrict__ C1, int ldc1, int nb1,
    const unsigned short* __restrict__ Ah2, const unsigned short* __restrict__ Al2,
    const unsigned short* __restrict__ Wh2, const unsigned short* __restrict__ Wl2,
    float* __restrict__ C2, int ldc2,
    int lda, int ldb, int K)
{
    __shared__ unsigned short Ash[128*64];
    __shared__ unsigned short Asl[128*64];
    __shared__ unsigned short Bsh[128*64];
    __shared__ unsigned short Bsl[128*64];
    int bx = blockIdx.x;
    if (bx < nb1)
        mfma2_body<0>(Ah1, Al1, lda, Wh1, Wl1, ldb, C1, ldc1, nullptr, K,
                      blockIdx.y*128, bx*128, Ash, Asl, Bsh, Bsl);
    else
        mfma2_body<0>(Ah2, Al2, lda, Wh2, Wl2, ldb, C2, ldc2, nullptr, K,
                      blockIdx.y*128, (bx-nb1)*128, Ash, Asl, Bsh, Bsl);
}

// ---------------- fp32 tile GEMM (dt_proj, K=48, EPI=2 softplus+bias) ----------
template<int EPI>
__global__ __launch_bounds__(256) void gemm_tile(
    const float* __restrict__ A, int lda,
    const float* __restrict__ W, int ldb,
    float* __restrict__ C, int ldc,
    const float* __restrict__ extra,
    int K)
{
    __shared__ float As[8][128];
    __shared__ float Bs[8][128];
    const int bm = blockIdx.y * 128;
    const int bn = blockIdx.x * 128;
    const int tid = threadIdx.x;
    const int lr = tid >> 1;
    const int lh = (tid & 1) * 4;
    const int tr = tid >> 4;
    const int tc = tid & 15;

    float acc[8][8];
    #pragma unroll
    for (int i = 0; i < 8; i++)
        #pragma unroll
        for (int j = 0; j < 8; j++) acc[i][j] = 0.f;

    const float* Arow = A + (size_t)(bm + lr)*lda + lh;
    const float* Wrow = W + (size_t)(bn + lr)*ldb + lh;

    for (int k0 = 0; k0 < K; k0 += 8) {
        float4 av = *(const float4*)(Arow + k0);
        float4 wv = *(const float4*)(Wrow + k0);
        __syncthreads();
        As[lh+0][lr] = av.x; As[lh+1][lr] = av.y; As[lh+2][lr] = av.z; As[lh+3][lr] = av.w;
        Bs[lh+0][lr] = wv.x; Bs[lh+1][lr] = wv.y; Bs[lh+2][lr] = wv.z; Bs[lh+3][lr] = wv.w;
        __syncthreads();
        #pragma unroll
        for (int k = 0; k < 8; k++) {
            float a[8], b[8];
            *(float4*)(a)   = *(const float4*)&As[k][tr*8];
            *(float4*)(a+4) = *(const float4*)&As[k][tr*8+4];
            *(float4*)(b)   = *(const float4*)&Bs[k][tc*8];
            *(float4*)(b+4) = *(const float4*)&Bs[k][tc*8+4];
            #pragma unroll
            for (int i = 0; i < 8; i++)
                #pragma unroll
                for (int j = 0; j < 8; j++)
                    acc[i][j] = fmaf(a[i], b[j], acc[i][j]);
        }
    }

    #pragma unroll
    for (int i = 0; i < 8; i++) {
        int row = bm + tr*8 + i;
        float* crow = C + (size_t)row*ldc + bn + tc*8;
        float v[8];
        if (EPI == 2) {
            const float* bia = extra + bn + tc*8;
            #pragma unroll
            for (int j = 0; j < 8; j++) v[j] = softplusf_(acc[i][j] + bia[j]);
        } else {
            #pragma unroll
            for (int j = 0; j < 8; j++) v[j] = acc[i][j];
        }
        *(float4*)(crow)   = make_float4(v[0],v[1],v[2],v[3]);
        *(float4*)(crow+4) = make_float4(v[4],v[5],v[6],v[7]);
    }
}

// ---------------- fused skinny split-K: x_dbl (64 cols) + C (16 cols) --------
// grid: x = 5 (0..3 -> x_proj 16-col chunks on A1; 4 -> c_proj on A2),
//       y = BL/64, z = KSPLIT. partial[z][m][NXD]
__global__ __launch_bounds__(256) void gemm_skinny2(
    const float* __restrict__ A1, const float* __restrict__ A2, int lda,
    const float* __restrict__ W1, const float* __restrict__ W2, int ldb,
    float* __restrict__ partial, int K)
{
    int klen = K / gridDim.z;
    int kbeg = blockIdx.z * klen;
    __shared__ float As[64][36];
    __shared__ float Ws[16][36];
    int tid = threadIdx.x;
    int bx = blockIdx.x;
    bool isC = (bx == 4);
    const float* A = isC ? A2 : A1;
    const float* W = isC ? W2 : W1;
    int bn = isC ? 0 : bx*16;
    int colbase = isC ? 64 : bx*16;
    int bm = blockIdx.y*64;
    int ar = tid >> 2, ak = (tid & 3)*8;
    int wr = tid >> 4, wk = (tid & 15)*2;
    int tr = tid >> 4, tc = tid & 15;

    float acc[4] = {0.f,0.f,0.f,0.f};
    for (int k0 = kbeg; k0 < kbeg + klen; k0 += 32) {
        float4 a0 = *(const float4*)(A + (size_t)(bm+ar)*lda + k0 + ak);
        float4 a1 = *(const float4*)(A + (size_t)(bm+ar)*lda + k0 + ak + 4);
        float2 wv = *(const float2*)(W + (size_t)(bn+wr)*ldb + k0 + wk);
        __syncthreads();
        *(float4*)&As[ar][ak]   = a0;
        *(float4*)&As[ar][ak+4] = a1;
        Ws[wr][wk] = wv.x; Ws[wr][wk+1] = wv.y;
        __syncthreads();
        #pragma unroll
        for (int k = 0; k < 32; k += 4) {
            float4 wv4 = *(const float4*)&Ws[tc][k];
            #pragma unroll
            for (int i = 0; i < 4; i++) {
                float4 av4 = *(const float4*)&As[tr*4+i][k];
                acc[i] = fmaf(av4.x, wv4.x, acc[i]);
                acc[i] = fmaf(av4.y, wv4.y, acc[i]);
                acc[i] = fmaf(av4.z, wv4.z, acc[i]);
                acc[i] = fmaf(av4.w, wv4.w, acc[i]);
            }
        }
    }
    #pragma unroll
    for (int i = 0; i < 4; i++)
        partial[((size_t)blockIdx.z*BL + bm + tr*4 + i)*NXD + colbase + tc] = acc[i];
}

__global__ void reduce_splitk(const float* __restrict__ partial, float* __restrict__ out, int MN)
{
    int i = blockIdx.x*256 + threadIdx.x;
    if (i >= MN) return;
    float s = 0.f;
    #pragma unroll
    for (int z = 0; z < KSPLIT; z++) s += partial[(size_t)z*MN + i];
    out[i] = s;
}

// ---------------- depthwise causal conv (k=4) + bias + silu ----------------
__global__ void conv_silu_kernel(const float* __restrict__ xr, const float* __restrict__ cw,
                                 const float* __restrict__ cb, float* __restrict__ t)
{
    int i = blockIdx.x*256 + threadIdx.x;     // over BL*DI
    if (i >= BL*DI) return;
    int d = i % DI; int bl = i / DI; int l = bl % L_; int b = bl / L_;
    const float* base = xr + (size_t)b*L_*(2*DI);
    float acc = cb[d];
    #pragma unroll
    for (int q = 0; q < 4; q++) {
        int ll = l - 3 + q;
        if (ll >= 0) acc = fmaf(base[(size_t)ll*(2*DI) + d], cw[d*4+q], acc);
    }
    t[i] = siluf_(acc);
}

// ---------------- chunked selective scan ----------------
__global__ void scan_p1(const float* __restrict__ delta, const float* __restrict__ t,
                        const float* __restrict__ xdbl, const float* __restrict__ A_log,
                        float* __restrict__ Aprod, float* __restrict__ Bacc)
{
    int idx = blockIdx.x*256 + threadIdx.x;   // (b*NCH + c)*DI + d
    if (idx >= B_*NCH*DI) return;
    int d = idx % DI; int c = (idx/DI) % NCH; int b = idx/(DI*NCH);
    float Ad[16];
    #pragma unroll
    for (int n = 0; n < 16; n++) Ad[n] = -expf(A_log[d*16+n]);
    float P[16], S[16];
    #pragma unroll
    for (int n = 0; n < 16; n++) { P[n] = 1.f; S[n] = 0.f; }
    for (int s = 0; s < LCH; s++) {
        int bl = b*L_ + c*LCH + s;
        float dt = delta[(size_t)bl*DI + d];
        float u  = t[(size_t)bl*DI + d];
        const float4* Bp4 = (const float4*)(xdbl + (size_t)bl*NXD + 48);
        float Bv[16];
        #pragma unroll
        for (int q = 0; q < 4; q++) {
            float4 bv = Bp4[q];
            Bv[q*4+0]=bv.x; Bv[q*4+1]=bv.y; Bv[q*4+2]=bv.z; Bv[q*4+3]=bv.w;
        }
        float du = dt*u;
        #pragma unroll
        for (int n = 0; n < 16; n++) {
            float a  = expf(dt*Ad[n]);
            P[n] *= a;
            S[n] = fmaf(a, S[n], du*Bv[n]);
        }
    }
    size_t o = (size_t)idx*16;
    #pragma unroll
    for (int n = 0; n < 16; n++) { Aprod[o+n] = P[n]; Bacc[o+n] = S[n]; }
}

__global__ void scan_p2(const float* __restrict__ Aprod, const float* __restrict__ Bacc,
                        float* __restrict__ Hinit)
{
    int idx = blockIdx.x*256 + threadIdx.x;   // b*DI + d
    if (idx >= B_*DI) return;
    int d = idx % DI, b = idx / DI;
    float h[16];
    #pragma unroll
    for (int n = 0; n < 16; n++) h[n] = 0.f;
    for (int c = 0; c < NCH; c++) {
        size_t o = (((size_t)b*NCH + c)*DI + d)*16;
        #pragma unroll
        for (int n = 0; n < 16; n++) Hinit[o+n] = h[n];
        #pragma unroll
        for (int n = 0; n < 16; n++) h[n] = fmaf(Aprod[o+n], h[n], Bacc[o+n]);
    }
}

// pass3: replay + fuse y = scan + u*D, z = y*silu(res) -> bf16 hi/lo out
__global__ void scan_p3(const float* __restrict__ delta, const float* __restrict__ t,
                        const float* __restrict__ xdbl,
                        const float* __restrict__ A_log, const float* __restrict__ Dp,
                        const float* __restrict__ Hinit, const float* __restrict__ xr,
                        unsigned short* __restrict__ zh, unsigned short* __restrict__ zl)
{
    int idx = blockIdx.x*256 + threadIdx.x;
    if (idx >= B_*NCH*DI) return;
    int d = idx % DI; int c = (idx/DI) % NCH; int b = idx/(DI*NCH);
    float Ad[16];
    #pragma unroll
    for (int n = 0; n < 16; n++) Ad[n] = -expf(A_log[d*16+n]);
    float h[16];
    size_t ho = (size_t)idx*16;
    #pragma unroll
    for (int n = 0; n < 16; n++) h[n] = Hinit[ho+n];
    float Dd = Dp[d];
    for (int s = 0; s < LCH; s++) {
        int bl = b*L_ + c*LCH + s;
        float dt = delta[(size_t)bl*DI + d];
        float u  = t[(size_t)bl*DI + d];
        const float4* Bp4 = (const float4*)(xdbl + (size_t)bl*NXD + 48);
        const float4* Cp4 = (const float4*)(xdbl + (size_t)bl*NXD + 64);
        float Bv[16], Cv[16];
        #pragma unroll
        for (int q = 0; q < 4; q++) {
            float4 bv = Bp4[q]; float4 cv = Cp4[q];
            Bv[q*4+0]=bv.x; Bv[q*4+1]=bv.y; Bv[q*4+2]=bv.z; Bv[q*4+3]=bv.w;
            Cv[q*4+0]=cv.x; Cv[q*4+1]=cv.y; Cv[q*4+2]=cv.z; Cv[q*4+3]=cv.w;
        }
        float du = dt*u;
        float y = 0.f;
        #pragma unroll
        for (int n = 0; n < 16; n++) {
            float a = expf(dt*Ad[n]);
            h[n] = fmaf(a, h[n], du*Bv[n]);
            y = fmaf(h[n], Cv[n], y);
        }
        y = fmaf(u, Dd, y);
        float r = xr[(size_t)bl*(2*DI) + DI + d];
        float zv = y * siluf_(r);
        unsigned short hh = f2bf(zv);
        zh[(size_t)bl*DI + d] = hh;
        zl[(size_t)bl*DI + d] = f2bf(zv - bf2f(hh));
    }
}

// ---------------- host ----------------
extern "C" void kernel_launch(void* const* d_in, const int* in_sizes, int n_in,
                              void* d_out, int out_size, void* d_ws, size_t ws_size,
                              hipStream_t stream)
{
    const int*   text     = (const int*)  d_in[0];
    const float* visual   = (const float*)d_in[1];
    const float* emb      = (const float*)d_in[2];
    const float* norm_w   = (const float*)d_in[3];
    const float* norm_f_w = (const float*)d_in[4];
    const float* in_proj  = (const float*)d_in[5];
    const float* in_proj2 = (const float*)d_in[6];
    const float* conv_w   = (const float*)d_in[7];
    const float* conv_b   = (const float*)d_in[8];
    const float* x_proj   = (const float*)d_in[9];
    const float* c_proj   = (const float*)d_in[10];
    const float* dt_w     = (const float*)d_in[11];
    const float* dt_b     = (const float*)d_in[12];
    const float* A_log    = (const float*)d_in[13];
    const float* Dp       = (const float*)d_in[14];
    const float* out_proj = (const float*)d_in[15];
    float* out = (float*)d_out;

    // workspace layout (floats first)
    float* ws = (float*)d_ws;
    size_t off = 0;
    float* x     = ws + off; off += (size_t)BL*DM;
    float* xr    = ws + off; off += (size_t)BL*2*DI;
    float* vin   = ws + off; off += (size_t)BL*DI;
    float* tb    = ws + off; off += (size_t)BL*DI;
    float* dl    = ws + off; off += (size_t)BL*DI;
    float* xdbl  = ws + off; off += (size_t)BL*NXD;
    float* Aprod = ws + off; off += (size_t)B_*NCH*DI*DS;
    float* Bacc  = ws + off; off += (size_t)B_*NCH*DI*DS;
    float* Hinit = ws + off; off += (size_t)B_*NCH*DI*DS;
    float* part  = ws + off; off += (size_t)KSPLIT*BL*NXD;

    unsigned short* bfb = (unsigned short*)(ws + off);
    size_t bo = 0;
    unsigned short* emb_bf = bfb + bo; bo += (size_t)VOC*DM;
    unsigned short* wA_h   = bfb + bo; bo += (size_t)2*DI*DM;
    unsigned short* wA_l   = bfb + bo; bo += (size_t)2*DI*DM;
    unsigned short* wB_h   = bfb + bo; bo += (size_t)DI*DM;
    unsigned short* wB_l   = bfb + bo; bo += (size_t)DI*DM;
    unsigned short* wO_h   = bfb + bo; bo += (size_t)DM*DI;
    unsigned short* wO_l   = bfb + bo; bo += (size_t)DM*DI;
    unsigned short* q_h    = bfb + bo; bo += (size_t)BL*DM;
    unsigned short* q_l    = bfb + bo; bo += (size_t)BL*DM;
    unsigned short* v_h    = bfb + bo; bo += (size_t)BL*DM;
    unsigned short* v_l    = bfb + bo; bo += (size_t)BL*DM;
    unsigned short* z_h    = bfb + bo; bo += (size_t)BL*DI;
    unsigned short* z_l    = bfb + bo; bo += (size_t)BL*DI;
    unsigned short* xn_bf  = bfb + bo; bo += (size_t)BL*DM;

    dim3 blk(256);
    dim3 cgrid(2048);

    // embedding cast once (lm_head B operand)
    cast_bf16_kernel<<<cgrid, blk, 0, stream>>>(emb, emb_bf, VOC*DM/4);

    embed_kernel<<<dim3((BL*DM)/256), blk, 0, stream>>>(text, emb, x);

    for (int i = 0; i < NL; i++) {
        const float* nw = norm_w + (size_t)i*DM;

        // q = rmsnorm(x), v = rmsnorm(visual) -> hi/lo, one dispatch
        rmsnorm_dual_kernel<<<dim3(2*BL), blk, 0, stream>>>(
            x, visual, nw, q_h, q_l, v_h, v_l);

        // per-layer weight hi/lo casts, one dispatch
        cast_pair3_kernel<<<cgrid, blk, 0, stream>>>(
            in_proj  + (size_t)i*2*DI*DM, wA_h, wA_l, 2*DI*DM/4,
            in_proj2 + (size_t)i*DI*DM,   wB_h, wB_l, DI*DM/4,
            out_proj + (size_t)i*DM*DI,   wO_h, wO_l, DM*DI/4);

        // xr = q @ in_proj^T (N=3072) ++ vin = v @ in_proj2^T (N=1536), fused
        gemm_mfma2_dual<<<dim3(2*DI/128 + DI/128, BL/128), blk, 0, stream>>>(
            q_h, q_l, wA_h, wA_l, xr, 2*DI, 2*DI/128,
            v_h, v_l, wB_h, wB_l, vin, DI,
            DM, DM, DM);

        conv_silu_kernel<<<dim3((BL*DI)/256), blk, 0, stream>>>(
            xr, conv_w + (size_t)i*DI*4, conv_b + (size_t)i*DI, tb);

        // x_dbl (t @ x_proj^T) ++ C (vin @ c_proj^T), fused split-K -> xdbl[BL][80]
        gemm_skinny2<<<dim3(5, BL/64, KSPLIT), blk, 0, stream>>>(
            tb, vin, DI, x_proj + (size_t)i*(DR+DS)*DI, c_proj + (size_t)i*DS*DI, DI,
            part, DI);
        reduce_splitk<<<dim3((BL*NXD)/256), blk, 0, stream>>>(part, xdbl, BL*NXD);

        // delta = softplus(x_dbl[:, :48] @ dt_w^T + dt_b) fp32
        gemm_tile<2><<<dim3(DI/128, BL/128), blk, 0, stream>>>(
            xdbl, NXD, dt_w + (size_t)i*DI*DR, DR, dl, DI, dt_b + (size_t)i*DI, DR);

        // selective scan (chunked, 3 passes) -> z hi/lo
        const float* Al = A_log + (size_t)i*DI*DS;
        scan_p1<<<dim3((B_*NCH*DI)/256), blk, 0, stream>>>(dl, tb, xdbl, Al, Aprod, Bacc);
        scan_p2<<<dim3((B_*DI+255)/256), blk, 0, stream>>>(Aprod, Bacc, Hinit);
        scan_p3<<<dim3((B_*NCH*DI)/256), blk, 0, stream>>>(dl, tb, xdbl, Al,
            Dp + (size_t)i*DI, Hinit, xr, z_h, z_l);

        // x = z @ out_proj^T + x (split precision)
        gemm_mfma2<1><<<dim3(DM/128, BL/128), blk, 0, stream>>>(
            z_h, z_l, DI, wO_h, wO_l, DI, x, DM, x, DI);
    }

    rmsnorm_bf_kernel<<<dim3(BL), blk, 0, stream>>>(x, norm_f_w, xn_bf);
    // logits = xn @ emb^T (2048 x 32000, K=768), grid x=M-blocks, y=N-blocks
    gemm_head<<<dim3(BL/128, VOC/128), blk, 0, stream>>>(
        xn_bf, DM, emb_bf, DM, out, VOC, DM);
}